// Round 14
// baseline (370.748 us; speedup 1.0000x reference)
//
#include <hip/hip_runtime.h>

#define DIM 1024
#define SEQ 2048

typedef __attribute__((ext_vector_type(8))) short bf16x8;
typedef __attribute__((ext_vector_type(16))) float f32x16;
typedef __attribute__((ext_vector_type(4))) unsigned short us4;
typedef __attribute__((ext_vector_type(4))) _Float16 h4;

__device__ __forceinline__ unsigned short f2bf(float f) {
    union { float f; unsigned int u; } v; v.f = f;
    unsigned int r = (v.u + 0x7FFFu + ((v.u >> 16) & 1u)) >> 16;
    return (unsigned short)r;
}

#define GLOAD(gp, lp) __builtin_amdgcn_global_load_lds( \
    (const __attribute__((address_space(1))) unsigned int*)(gp), \
    (__attribute__((address_space(3))) unsigned int*)(lp), 16, 0, 0)

#define MFMA32(a, b, c) __builtin_amdgcn_mfma_f32_32x32x16_bf16((a), (b), (c), 0, 0, 0)

__global__ __launch_bounds__(256) void cast_f32_bf16(const float* __restrict__ src,
                                                     unsigned short* __restrict__ dst, int n) {
    int i = (blockIdx.x * 256 + threadIdx.x) * 8;
    if (i >= n) return;
    float4 a = *(const float4*)(src + i);
    float4 b = *(const float4*)(src + i + 4);
    us4 lo = { f2bf(a.x), f2bf(a.y), f2bf(a.z), f2bf(a.w) };
    us4 hi = { f2bf(b.x), f2bf(b.y), f2bf(b.z), f2bf(b.w) };
    *(us4*)(dst + i) = lo;
    *(us4*)(dst + i + 4) = hi;
}

// ---------------------------------------------------------------------------
// 128x256 GEMM core, 32x32x16 MFMA, BK=32. LDS-instruction-minimized:
// diagnosis R8/R11/R12 -> LDS pipe (12 cyc per wave-wide access) was the
// wall (rho = LDS_cyc/MFMA_cyc = 1.3-2.2). Here:
//   * A (128 rows, shared by ALL 4 waves) via global_load_lds, swizzled LDS,
//     2 dbufs x 8 KiB = 16 KiB static.
//   * B: each wave's private 64-col panel loaded DIRECTLY global->VGPR
//     (prefetched 1 K-tile ahead; panels are L2-resident). Zero LDS cost.
// Per K32/block: LDS = 32 reads + 2 stages = 408 cyc vs MFMA 516 -> rho 0.79.
// 4 waves (wn 0..3), wave tile 128x64 (mi 0..3 x nj 0..1), acc 4x2 f32x16.
// VGPR ~190 -> launch_bounds(256,2) = 2 blocks/CU (anti-phase TLP).
// Swizzle (R7/R12-verified): slot s of 64B row r holds chunk s^((r>>1)&3).
// ---------------------------------------------------------------------------
__device__ __forceinline__ void gemm128x256_core(
    const unsigned short* __restrict__ A, const unsigned short* __restrict__ B,
    int lda, int ldb, int K, char* smem, f32x16 acc[4][2])
{
    const int tid = threadIdx.x;
    const int lane = tid & 63;
    const int wn = tid >> 6;                 // 0..3
    const int l31 = lane & 31, lhi = lane >> 5;

    // A staging: thread t -> rows t>>2 and 64+(t>>2); slot t&3 <- chunk (t&3)^((row>>1)&3)
    const int schunk = ((tid & 3) ^ ((tid >> 3) & 3)) * 8;
    const unsigned short* paw = A + (size_t)(tid >> 2) * lda + schunk;
    const int doff = tid * 16;

    const int fsw = (l31 >> 1) & 3;
    int csw[4];
#pragma unroll
    for (int c = 0; c < 4; c++) csw[c] = (c ^ fsw) * 16;
    const int ab0 = l31 * 64;                // + mi*2048 + csw[ks*2+lhi]

    // B direct: lane reads row wn*64 + nj*32 + l31, chunk ks*2+lhi
    const unsigned short* pb = B + (size_t)(wn * 64 + l31) * ldb + lhi * 8;
    const size_t bnj = (size_t)32 * ldb;

    const int NT = K >> 5;

#define SA(bb, kt) do { \
    GLOAD(paw + (kt),                     smem + (bb) + doff); \
    GLOAD(paw + (kt) + (size_t)64 * lda,  smem + (bb) + 4096 + doff); \
} while (0)
#define LB(dst, kt) do { \
    dst[0][0] = *(const bf16x8*)(pb + (kt)); \
    dst[0][1] = *(const bf16x8*)(pb + (kt) + 16); \
    dst[1][0] = *(const bf16x8*)(pb + bnj + (kt)); \
    dst[1][1] = *(const bf16x8*)(pb + bnj + (kt) + 16); \
} while (0)
#define TILE(bufoff, bcur) do { \
    bf16x8 a[4][2]; \
    _Pragma("unroll") \
    for (int mi = 0; mi < 4; mi++) { \
        a[mi][0] = *(const bf16x8*)(smem + (bufoff) + ab0 + mi * 2048 + csw[lhi]); \
        a[mi][1] = *(const bf16x8*)(smem + (bufoff) + ab0 + mi * 2048 + csw[2 + lhi]); \
    } \
    __builtin_amdgcn_s_setprio(1); \
    _Pragma("unroll") \
    for (int ks = 0; ks < 2; ks++) \
        _Pragma("unroll") \
        for (int mi = 0; mi < 4; mi++) \
            _Pragma("unroll") \
            for (int nj = 0; nj < 2; nj++) \
                acc[mi][nj] = MFMA32(a[mi][ks], bcur[nj][ks], acc[mi][nj]); \
    __builtin_amdgcn_s_setprio(0); \
    asm volatile("s_waitcnt vmcnt(0)" ::: "memory"); \
    __builtin_amdgcn_s_barrier(); \
} while (0)

    bf16x8 bA[2][2], bB[2][2];
    SA(0, 0);
    LB(bA, 0);
    asm volatile("s_waitcnt vmcnt(0)" ::: "memory");
    __builtin_amdgcn_s_barrier();

    for (int T = 0; T < NT; T += 2) {
        if (T + 1 < NT) { SA(8192, (T + 1) * 32); LB(bB, (T + 1) * 32); }
        TILE(0, bA);
        if (T + 1 < NT) {
            if (T + 2 < NT) { SA(0, (T + 2) * 32); LB(bA, (T + 2) * 32); }
            TILE(8192, bB);
        }
    }
#undef SA
#undef LB
#undef TILE
}

#define ACC_INIT() \
    f32x16 acc[4][2]; \
    _Pragma("unroll") for (int i = 0; i < 4; i++) \
    _Pragma("unroll") for (int jj = 0; jj < 2; jj++) acc[i][jj] = (f32x16){}; \

// C/D layout (32x32): row = (r&3) + 8*(r>>2) + 4*(lane>>5), col = lane&31.
// Wave tile: rows m0 + mi*32 + ..., cols n0 + wn*64 + nj*32 + l31.

// Fused q/k/v: 1536 blocks. bz: 0->q (scaled 1/32), 1->k, 2->v^T [B][D][S].
__global__ __launch_bounds__(256, 2) void gemm_qkv(
    const unsigned short* __restrict__ xb, const unsigned short* __restrict__ wb,
    const float* __restrict__ bq, const float* __restrict__ bk, const float* __restrict__ bv,
    unsigned short* __restrict__ qb, unsigned short* __restrict__ kb, unsigned short* __restrict__ vt)
{
    __shared__ char smem[16384];
    const int bid = blockIdx.x;
    const int lb = (bid & 7) * 192 + (bid >> 3);   // bijective, 1536 % 8 == 0
    const int bz = lb >> 9;                         // 0..2 (512 tiles per matrix)
    const int r0 = lb & 511;
    const int m0 = (r0 >> 2) * 128, n0 = (r0 & 3) * 256;
    const float* bias = (bz == 0) ? bq : ((bz == 1) ? bk : bv);
    ACC_INIT();
    gemm128x256_core(xb + (size_t)m0 * DIM, wb + (size_t)bz * DIM * DIM + (size_t)n0 * DIM,
                     DIM, DIM, DIM, smem, acc);
    const int lane = threadIdx.x & 63, wn = threadIdx.x >> 6;
    const int l31 = lane & 31, lhi = lane >> 5;
#pragma unroll
    for (int mi = 0; mi < 4; mi++)
#pragma unroll
        for (int nj = 0; nj < 2; nj++) {
            const int col = n0 + wn * 64 + nj * 32 + l31;
            const float bcol = bias[col];
            if (bz < 2) {
                unsigned short* C = (bz == 0) ? qb : kb;
                const float scale = (bz == 0) ? 0.03125f : 1.0f;
#pragma unroll
                for (int r = 0; r < 16; r++) {
                    const int row = m0 + mi * 32 + (r & 3) + 8 * (r >> 2) + 4 * lhi;
                    C[(size_t)row * DIM + col] = f2bf((acc[mi][nj][r] + bcol) * scale);
                }
            } else {
#pragma unroll
                for (int r4 = 0; r4 < 4; r4++) {
                    const int s0 = m0 + mi * 32 + 8 * r4 + 4 * lhi;
                    const int b = s0 >> 11, s = s0 & 2047;
                    us4 pk = { f2bf(acc[mi][nj][r4 * 4] + bcol),
                               f2bf(acc[mi][nj][r4 * 4 + 1] + bcol),
                               f2bf(acc[mi][nj][r4 * 4 + 2] + bcol),
                               f2bf(acc[mi][nj][r4 * 4 + 3] + bcol) };
                    *(us4*)&vt[((size_t)b << 21) + ((size_t)col << 11) + s] = pk;
                }
            }
        }
}

// S[b] = q[b] * k[b]^T (q pre-scaled), fp16 out. 1024 blocks (128/batch = XCD-aligned).
__global__ __launch_bounds__(256, 2) void gemm_qk(
    const unsigned short* __restrict__ qb, const unsigned short* __restrict__ kb,
    unsigned short* __restrict__ sb)
{
    __shared__ char smem[16384];
    const int bid = blockIdx.x;
    const int lb = (bid & 7) * 128 + (bid >> 3);
    const int b = lb >> 7;
    const int r0 = lb & 127;
    const int m0 = (r0 >> 3) * 128, n0 = (r0 & 7) * 256;
    ACC_INIT();
    gemm128x256_core(qb + ((size_t)b * SEQ + m0) * DIM, kb + ((size_t)b * SEQ + n0) * DIM,
                     DIM, DIM, DIM, smem, acc);
    const int lane = threadIdx.x & 63, wn = threadIdx.x >> 6;
    const int l31 = lane & 31, lhi = lane >> 5;
    _Float16* sh = (_Float16*)sb + (size_t)b * SEQ * SEQ;
#pragma unroll
    for (int mi = 0; mi < 4; mi++)
#pragma unroll
        for (int nj = 0; nj < 2; nj++) {
            const int col = n0 + wn * 64 + nj * 32 + l31;
#pragma unroll
            for (int r = 0; r < 16; r++) {
                const int row = m0 + mi * 32 + (r & 3) + 8 * (r >> 2) + 4 * lhi;
                sh[(size_t)row * SEQ + col] = (_Float16)acc[mi][nj][r];
            }
        }
}

// Row softmax fp16 -> normalized bf16 P in place
__global__ __launch_bounds__(256) void softmax_p(unsigned short* __restrict__ sb)
{
    const int lane = threadIdx.x & 63, wid = threadIdx.x >> 6;
    const size_t row = (size_t)blockIdx.x * 4 + wid;
    unsigned short* rp = sb + row * SEQ;
    float v[32];
#pragma unroll
    for (int j = 0; j < 8; j++) {
        h4 h = *(const h4*)(rp + (j * 64 + lane) * 4);
#pragma unroll
        for (int e = 0; e < 4; e++) v[j * 4 + e] = (float)h[e];
    }
    float m = -1e30f;
#pragma unroll
    for (int i = 0; i < 32; i++) m = fmaxf(m, v[i]);
#pragma unroll
    for (int msk = 1; msk <= 32; msk <<= 1) m = fmaxf(m, __shfl_xor(m, msk, 64));
    float s = 0.f;
#pragma unroll
    for (int i = 0; i < 32; i++) { v[i] = __expf(v[i] - m); s += v[i]; }
#pragma unroll
    for (int msk = 1; msk <= 32; msk <<= 1) s += __shfl_xor(s, msk, 64);
    float inv = 1.0f / s;
#pragma unroll
    for (int j = 0; j < 8; j++) {
        us4 pu = { f2bf(v[j * 4] * inv), f2bf(v[j * 4 + 1] * inv),
                   f2bf(v[j * 4 + 2] * inv), f2bf(v[j * 4 + 3] * inv) };
        *(us4*)(rp + (j * 64 + lane) * 4) = pu;
    }
}

// O[b] = P[b] * VT[b]^T, f32 out. 512 blocks.
__global__ __launch_bounds__(256, 2) void gemm_pv(
    const unsigned short* __restrict__ pb, const unsigned short* __restrict__ vt,
    float* __restrict__ out)
{
    __shared__ char smem[16384];
    const int bid = blockIdx.x;
    const int lb = (bid & 7) * 64 + (bid >> 3);
    const int b = lb >> 6;
    const int r0 = lb & 63;
    const int m0 = (r0 >> 2) * 128, n0 = (r0 & 3) * 256;
    ACC_INIT();
    gemm128x256_core(pb + ((size_t)b * SEQ + m0) * SEQ, vt + ((size_t)b * DIM + n0) * SEQ,
                     SEQ, SEQ, SEQ, smem, acc);
    const int lane = threadIdx.x & 63, wn = threadIdx.x >> 6;
    const int l31 = lane & 31, lhi = lane >> 5;
    float* O = out + (size_t)b * SEQ * DIM;
#pragma unroll
    for (int mi = 0; mi < 4; mi++)
#pragma unroll
        for (int nj = 0; nj < 2; nj++) {
            const int col = n0 + wn * 64 + nj * 32 + l31;
#pragma unroll
            for (int r = 0; r < 16; r++) {
                const int row = m0 + mi * 32 + (r & 3) + 8 * (r >> 2) + 4 * lhi;
                O[(size_t)row * DIM + col] = acc[mi][nj][r];
            }
        }
}

extern "C" void kernel_launch(void* const* d_in, const int* in_sizes, int n_in,
                              void* d_out, int out_size, void* d_ws, size_t ws_size,
                              hipStream_t stream) {
    const float* x  = (const float*)d_in[0];
    const float* Wq = (const float*)d_in[1];
    const float* bq = (const float*)d_in[2];
    const float* Wk = (const float*)d_in[3];
    const float* bk = (const float*)d_in[4];
    const float* Wv = (const float*)d_in[5];
    const float* bv = (const float*)d_in[6];
    float* out = (float*)d_out;
    char* ws = (char*)d_ws;

    unsigned short* xb = (unsigned short*)(ws);                  // 32 MiB  x bf16
    unsigned short* wb = (unsigned short*)(ws + 33554432);       //  6 MiB  Wq|Wk|Wv bf16
    unsigned short* qb = (unsigned short*)(ws + 39845888);       // 32 MiB  q bf16 (pre-scaled)
    unsigned short* kb = (unsigned short*)(ws + 73400320);       // 32 MiB  k bf16
    unsigned short* vt = (unsigned short*)(ws + 106954752);      // 32 MiB  v^T bf16 [B][D][S]
    unsigned short* sb = (unsigned short*)(ws + 140509184);      // 64 MiB  S fp16 -> P bf16

    cast_f32_bf16<<<dim3(8192), 256, 0, stream>>>(x, xb, 16777216);
    cast_f32_bf16<<<dim3(512), 256, 0, stream>>>(Wq, wb, 1048576);
    cast_f32_bf16<<<dim3(512), 256, 0, stream>>>(Wk, wb + 1048576, 1048576);
    cast_f32_bf16<<<dim3(512), 256, 0, stream>>>(Wv, wb + 2097152, 1048576);

    gemm_qkv<<<dim3(1536), 256, 0, stream>>>(xb, wb, bq, bk, bv, qb, kb, vt);
    gemm_qk<<<dim3(1024), 256, 0, stream>>>(qb, kb, sb);
    softmax_p<<<dim3(4096), 256, 0, stream>>>(sb);
    gemm_pv<<<dim3(512), 256, 0, stream>>>(sb, vt, out);
}

// Round 16
// 286.929 us; speedup vs baseline: 1.2921x; 1.2921x over previous
//
#include <hip/hip_runtime.h>

#define DIM 1024
#define SEQ 2048

typedef __attribute__((ext_vector_type(8))) short bf16x8;
typedef __attribute__((ext_vector_type(16))) float f32x16;
typedef __attribute__((ext_vector_type(4))) unsigned short us4;
typedef __attribute__((ext_vector_type(4))) _Float16 h4;

__device__ __forceinline__ unsigned short f2bf(float f) {
    union { float f; unsigned int u; } v; v.f = f;
    unsigned int r = (v.u + 0x7FFFu + ((v.u >> 16) & 1u)) >> 16;
    return (unsigned short)r;
}

#define GLOAD(gp, lp) __builtin_amdgcn_global_load_lds( \
    (const __attribute__((address_space(1))) unsigned int*)(gp), \
    (__attribute__((address_space(3))) unsigned int*)(lp), 16, 0, 0)

#define MFMA32(a, b, c) __builtin_amdgcn_mfma_f32_32x32x16_bf16((a), (b), (c), 0, 0, 0)

__global__ __launch_bounds__(256) void cast_f32_bf16(const float* __restrict__ src,
                                                     unsigned short* __restrict__ dst, int n) {
    int i = (blockIdx.x * 256 + threadIdx.x) * 8;
    if (i >= n) return;
    float4 a = *(const float4*)(src + i);
    float4 b = *(const float4*)(src + i + 4);
    us4 lo = { f2bf(a.x), f2bf(a.y), f2bf(a.z), f2bf(a.w) };
    us4 hi = { f2bf(b.x), f2bf(b.y), f2bf(b.z), f2bf(b.w) };
    *(us4*)(dst + i) = lo;
    *(us4*)(dst + i + 4) = hi;
}

// ---------------------------------------------------------------------------
// R8 core (proven best, 287us): 256x256 GEMM, 32x32x16 MFMA, BK=64, 128B LDS
// rows, 8-slot XOR swizzle (slot s of row r holds source chunk s^(r&7)).
// 512 thr = 8 waves (2M x 4N), per-wave 128x64 = 4x2 frags. 2 dbufs of 64 KiB
// (A[256][64] @0, B[256][64] @32768). Per K64 tile: vmcnt(0) BEFORE barrier
// (each wave drains its own DMAs; barrier certifies buffer complete), then two
// ks-halves each {12 ds_read_b128 || 4 gload staging of T+1 -> 16 MFMA under
// setprio}. Correctness invariant: wait-own-DMA -> barrier -> read.
// ---------------------------------------------------------------------------
__device__ __forceinline__ void gemm256_core(
    const unsigned short* __restrict__ A, const unsigned short* __restrict__ B,
    int lda, int ldb, int K, char* smem, f32x16 acc[4][2])
{
    const int tid = threadIdx.x;
    const int lane = tid & 63;
    const int wm = (tid >> 6) >> 2;          // 0..1
    const int wn = (tid >> 6) & 3;           // 0..3
    const int l31 = lane & 31, lhi = lane >> 5;

    // staging: thread t covers row (t>>3)+64h, slot t&7 holds chunk (t&7)^(row&7)
    const int schunk = ((tid & 7) ^ ((tid >> 3) & 7)) * 8;
    const unsigned short* paw = A + (size_t)(tid >> 3) * lda + schunk;
    const unsigned short* pbw = B + (size_t)(tid >> 3) * ldb + schunk;
    const int doff = tid * 16;

    const int key = l31 & 7;
    const int abase = (wm * 128 + l31) * 128;            // + mi*4096
    const int bbase = 32768 + (wn * 64 + l31) * 128;     // + nj*4096
    int csw[4];
#pragma unroll
    for (int ks = 0; ks < 4; ks++) csw[ks] = (((ks << 1) | lhi) ^ key) * 16;

    const int NT = K >> 6;

#define STAGE_A(bb, kt) do { \
    GLOAD(paw + (kt),                       smem + (bb) + doff); \
    GLOAD(paw + (kt) + (size_t)64  * lda,   smem + (bb) + 8192 + doff); \
    GLOAD(paw + (kt) + (size_t)128 * lda,   smem + (bb) + 16384 + doff); \
    GLOAD(paw + (kt) + (size_t)192 * lda,   smem + (bb) + 24576 + doff); \
} while (0)
#define STAGE_B(bb, kt) do { \
    GLOAD(pbw + (kt),                       smem + (bb) + 32768 + doff); \
    GLOAD(pbw + (kt) + (size_t)64  * ldb,   smem + (bb) + 40960 + doff); \
    GLOAD(pbw + (kt) + (size_t)128 * ldb,   smem + (bb) + 49152 + doff); \
    GLOAD(pbw + (kt) + (size_t)192 * ldb,   smem + (bb) + 57344 + doff); \
} while (0)

    STAGE_A(0, 0);
    STAGE_B(0, 0);

    for (int T = 0; T < NT; ++T) {
        asm volatile("s_waitcnt vmcnt(0)" ::: "memory");
        __builtin_amdgcn_s_barrier();
        const char* db = smem + (T & 1) * 65536;
        const int nb = ((T + 1) & 1) * 65536;
        bf16x8 a0[4], a1[4], b0[2], b1[2];

        // ---- ks half 0 (k 0..31) ----
#pragma unroll
        for (int mi = 0; mi < 4; mi++) {
            a0[mi] = *(const bf16x8*)(db + abase + mi * 4096 + csw[0]);
            a1[mi] = *(const bf16x8*)(db + abase + mi * 4096 + csw[1]);
        }
#pragma unroll
        for (int nj = 0; nj < 2; nj++) {
            b0[nj] = *(const bf16x8*)(db + bbase + nj * 4096 + csw[0]);
            b1[nj] = *(const bf16x8*)(db + bbase + nj * 4096 + csw[1]);
        }
        if (T + 1 < NT) STAGE_A(nb, (size_t)(T + 1) * 64);
        __builtin_amdgcn_s_setprio(1);
#pragma unroll
        for (int mi = 0; mi < 4; mi++)
#pragma unroll
            for (int nj = 0; nj < 2; nj++)
                acc[mi][nj] = MFMA32(a0[mi], b0[nj], acc[mi][nj]);
#pragma unroll
        for (int mi = 0; mi < 4; mi++)
#pragma unroll
            for (int nj = 0; nj < 2; nj++)
                acc[mi][nj] = MFMA32(a1[mi], b1[nj], acc[mi][nj]);
        __builtin_amdgcn_s_setprio(0);

        // ---- ks half 1 (k 32..63) ----
#pragma unroll
        for (int mi = 0; mi < 4; mi++) {
            a0[mi] = *(const bf16x8*)(db + abase + mi * 4096 + csw[2]);
            a1[mi] = *(const bf16x8*)(db + abase + mi * 4096 + csw[3]);
        }
#pragma unroll
        for (int nj = 0; nj < 2; nj++) {
            b0[nj] = *(const bf16x8*)(db + bbase + nj * 4096 + csw[2]);
            b1[nj] = *(const bf16x8*)(db + bbase + nj * 4096 + csw[3]);
        }
        if (T + 1 < NT) STAGE_B(nb, (size_t)(T + 1) * 64);
        __builtin_amdgcn_s_setprio(1);
#pragma unroll
        for (int mi = 0; mi < 4; mi++)
#pragma unroll
            for (int nj = 0; nj < 2; nj++)
                acc[mi][nj] = MFMA32(a0[mi], b0[nj], acc[mi][nj]);
#pragma unroll
        for (int mi = 0; mi < 4; mi++)
#pragma unroll
            for (int nj = 0; nj < 2; nj++)
                acc[mi][nj] = MFMA32(a1[mi], b1[nj], acc[mi][nj]);
        __builtin_amdgcn_s_setprio(0);
    }
#undef STAGE_A
#undef STAGE_B
}

#define ACC_INIT() \
    f32x16 acc[4][2]; \
    _Pragma("unroll") for (int i = 0; i < 4; i++) \
    _Pragma("unroll") for (int jj = 0; jj < 2; jj++) acc[i][jj] = (f32x16){}; \

// C/D layout (32x32): row = (r&3) + 8*(r>>2) + 4*(lane>>5), col = lane&31.

// BZ=0: q = (xW^T + b)/32, bf16. BZ=1: k, bf16. BZ=2: v -> vt [B][D][S] bf16.
template<int BZ>
__global__ __launch_bounds__(512, 2) void gemm_qkv_t(
    const unsigned short* __restrict__ xb, const unsigned short* __restrict__ w,
    const float* __restrict__ bias, unsigned short* __restrict__ C)
{
    extern __shared__ char smem[];
    const int bid = blockIdx.x;
    const int lb = (bid & 7) * 32 + (bid >> 3);   // 256 blocks, XCD-chunked
    const int m0 = (lb >> 2) * 256, n0 = (lb & 3) * 256;
    ACC_INIT();
    gemm256_core(xb + (size_t)m0 * DIM, w + (size_t)n0 * DIM, DIM, DIM, DIM, smem, acc);
    const int lane = threadIdx.x & 63, wid = threadIdx.x >> 6;
    const int wm = wid >> 2, wn = wid & 3;
    const int l31 = lane & 31, lhi = lane >> 5;
#pragma unroll
    for (int mi = 0; mi < 4; mi++)
#pragma unroll
        for (int nj = 0; nj < 2; nj++) {
            const int col = n0 + wn * 64 + nj * 32 + l31;
            const float bcol = bias[col];
            if (BZ < 2) {
                const float scale = (BZ == 0) ? 0.03125f : 1.0f;
#pragma unroll
                for (int r = 0; r < 16; r++) {
                    const int row = m0 + wm * 128 + mi * 32 + (r & 3) + 8 * (r >> 2) + 4 * lhi;
                    C[(size_t)row * DIM + col] = f2bf((acc[mi][nj][r] + bcol) * scale);
                }
            } else {
#pragma unroll
                for (int r4 = 0; r4 < 4; r4++) {
                    const int s0 = m0 + wm * 128 + mi * 32 + 8 * r4 + 4 * lhi;
                    const int b = s0 >> 11, s = s0 & 2047;
                    us4 pk = { f2bf(acc[mi][nj][r4 * 4] + bcol),
                               f2bf(acc[mi][nj][r4 * 4 + 1] + bcol),
                               f2bf(acc[mi][nj][r4 * 4 + 2] + bcol),
                               f2bf(acc[mi][nj][r4 * 4 + 3] + bcol) };
                    *(us4*)&C[((size_t)b << 21) + ((size_t)col << 11) + s] = pk;
                }
            }
        }
}

// S[b] = q[b] * k[b]^T (q pre-scaled), fp16 out [B][S][S]
__global__ __launch_bounds__(512, 2) void gemm_qk(
    const unsigned short* __restrict__ qb, const unsigned short* __restrict__ kb,
    unsigned short* __restrict__ sb)
{
    extern __shared__ char smem[];
    const int bid = blockIdx.x;
    const int lb = (bid & 7) * 64 + (bid >> 3);
    const int b = lb >> 6;
    const int r0 = lb & 63;
    const int m0 = (r0 >> 3) * 256, n0 = (r0 & 7) * 256;
    ACC_INIT();
    gemm256_core(qb + ((size_t)b * SEQ + m0) * DIM, kb + ((size_t)b * SEQ + n0) * DIM,
                 DIM, DIM, DIM, smem, acc);
    const int lane = threadIdx.x & 63, wid = threadIdx.x >> 6;
    const int wm = wid >> 2, wn = wid & 3;
    const int l31 = lane & 31, lhi = lane >> 5;
    _Float16* sh = (_Float16*)sb + (size_t)b * SEQ * SEQ;
#pragma unroll
    for (int mi = 0; mi < 4; mi++)
#pragma unroll
        for (int nj = 0; nj < 2; nj++) {
            const int col = n0 + wn * 64 + nj * 32 + l31;
#pragma unroll
            for (int r = 0; r < 16; r++) {
                const int row = m0 + wm * 128 + mi * 32 + (r & 3) + 8 * (r >> 2) + 4 * lhi;
                sh[(size_t)row * SEQ + col] = (_Float16)acc[mi][nj][r];
            }
        }
}

// Row softmax fp16 -> normalized bf16 P in place
__global__ __launch_bounds__(256) void softmax_p(unsigned short* __restrict__ sb)
{
    const int lane = threadIdx.x & 63, wid = threadIdx.x >> 6;
    const size_t row = (size_t)blockIdx.x * 4 + wid;
    unsigned short* rp = sb + row * SEQ;
    float v[32];
#pragma unroll
    for (int j = 0; j < 8; j++) {
        h4 h = *(const h4*)(rp + (j * 64 + lane) * 4);
#pragma unroll
        for (int e = 0; e < 4; e++) v[j * 4 + e] = (float)h[e];
    }
    float m = -1e30f;
#pragma unroll
    for (int i = 0; i < 32; i++) m = fmaxf(m, v[i]);
#pragma unroll
    for (int msk = 1; msk <= 32; msk <<= 1) m = fmaxf(m, __shfl_xor(m, msk, 64));
    float s = 0.f;
#pragma unroll
    for (int i = 0; i < 32; i++) { v[i] = __expf(v[i] - m); s += v[i]; }
#pragma unroll
    for (int msk = 1; msk <= 32; msk <<= 1) s += __shfl_xor(s, msk, 64);
    float inv = 1.0f / s;
#pragma unroll
    for (int j = 0; j < 8; j++) {
        us4 pu = { f2bf(v[j * 4] * inv), f2bf(v[j * 4 + 1] * inv),
                   f2bf(v[j * 4 + 2] * inv), f2bf(v[j * 4 + 3] * inv) };
        *(us4*)(rp + (j * 64 + lane) * 4) = pu;
    }
}

// O[b] = P[b] * VT[b]^T, f32 out
__global__ __launch_bounds__(512, 2) void gemm_pv(
    const unsigned short* __restrict__ pb, const unsigned short* __restrict__ vt,
    float* __restrict__ out)
{
    extern __shared__ char smem[];
    const int bid = blockIdx.x;
    const int lb = (bid & 7) * 32 + (bid >> 3);
    const int b = lb >> 5;
    const int r0 = lb & 31;
    const int m0 = (r0 >> 2) * 256, n0 = (r0 & 3) * 256;
    ACC_INIT();
    gemm256_core(pb + ((size_t)b * SEQ + m0) * SEQ, vt + ((size_t)b * DIM + n0) * SEQ,
                 SEQ, SEQ, SEQ, smem, acc);
    const int lane = threadIdx.x & 63, wid = threadIdx.x >> 6;
    const int wm = wid >> 2, wn = wid & 3;
    const int l31 = lane & 31, lhi = lane >> 5;
    float* O = out + (size_t)b * SEQ * DIM;
#pragma unroll
    for (int mi = 0; mi < 4; mi++)
#pragma unroll
        for (int nj = 0; nj < 2; nj++) {
            const int col = n0 + wn * 64 + nj * 32 + l31;
#pragma unroll
            for (int r = 0; r < 16; r++) {
                const int row = m0 + wm * 128 + mi * 32 + (r & 3) + 8 * (r >> 2) + 4 * lhi;
                O[(size_t)row * DIM + col] = acc[mi][nj][r];
            }
        }
}

extern "C" void kernel_launch(void* const* d_in, const int* in_sizes, int n_in,
                              void* d_out, int out_size, void* d_ws, size_t ws_size,
                              hipStream_t stream) {
    const float* x  = (const float*)d_in[0];
    const float* Wq = (const float*)d_in[1];
    const float* bq = (const float*)d_in[2];
    const float* Wk = (const float*)d_in[3];
    const float* bk = (const float*)d_in[4];
    const float* Wv = (const float*)d_in[5];
    const float* bv = (const float*)d_in[6];
    float* out = (float*)d_out;
    char* ws = (char*)d_ws;

    unsigned short* xb = (unsigned short*)(ws);                  // 32 MiB  x bf16
    unsigned short* wb = (unsigned short*)(ws + 33554432);       //  6 MiB  Wq|Wk|Wv bf16
    unsigned short* qb = (unsigned short*)(ws + 39845888);       // 32 MiB  q bf16 (pre-scaled)
    unsigned short* kb = (unsigned short*)(ws + 73400320);       // 32 MiB  k bf16
    unsigned short* vt = (unsigned short*)(ws + 106954752);      // 32 MiB  v^T bf16 [B][D][S]
    unsigned short* sb = (unsigned short*)(ws + 140509184);      // 64 MiB  S fp16 -> P bf16

    cast_f32_bf16<<<dim3(8192), 256, 0, stream>>>(x, xb, 16777216);
    cast_f32_bf16<<<dim3(512), 256, 0, stream>>>(Wq, wb, 1048576);
    cast_f32_bf16<<<dim3(512), 256, 0, stream>>>(Wk, wb + 1048576, 1048576);
    cast_f32_bf16<<<dim3(512), 256, 0, stream>>>(Wv, wb + 2097152, 1048576);

    hipFuncSetAttribute((const void*)gemm_qkv_t<0>, hipFuncAttributeMaxDynamicSharedMemorySize, 131072);
    hipFuncSetAttribute((const void*)gemm_qkv_t<1>, hipFuncAttributeMaxDynamicSharedMemorySize, 131072);
    hipFuncSetAttribute((const void*)gemm_qkv_t<2>, hipFuncAttributeMaxDynamicSharedMemorySize, 131072);
    hipFuncSetAttribute((const void*)gemm_qk,  hipFuncAttributeMaxDynamicSharedMemorySize, 131072);
    hipFuncSetAttribute((const void*)gemm_pv,  hipFuncAttributeMaxDynamicSharedMemorySize, 131072);

    gemm_qkv_t<0><<<dim3(256), 512, 131072, stream>>>(xb, wb,           bq, qb);
    gemm_qkv_t<1><<<dim3(256), 512, 131072, stream>>>(xb, wb + 1048576, bk, kb);
    gemm_qkv_t<2><<<dim3(256), 512, 131072, stream>>>(xb, wb + 2097152, bv, vt);
    gemm_qk<<<dim3(512), 512, 131072, stream>>>(qb, kb, sb);
    softmax_p<<<dim3(4096), 256, 0, stream>>>(sb);
    gemm_pv<<<dim3(256), 512, 131072, stream>>>(sb, vt, out);
}